// Round 1
// baseline (128.967 us; speedup 1.0000x reference)
//
#include <hip/hip_runtime.h>

// multi_triples_lstm v15: barrier-free recurrence.
// Each wave owns 16 batches and computes ALL 32 LSTM units itself:
// 8 MFMA tiles (4 gates x 2 unit-halves) with a W-row permutation chosen so
// computed h lands exactly in the next h-MFMA's B-fragment lane layout.
// -> zero cross-wave exchange, zero per-step __syncthreads, zero LDS h traffic.
// 64-thread blocks (1 wave), 2048 blocks, 8 waves/CU (2/SIMD, ~200 VGPR).
//
// W-row permutation: acc a in 0..7: gate g = a>>1 (i,f,g,o order), C-row m ->
// unit u(m) = 8*(m>>2) + 4*(a&1) + (m&3); canonical W row n = g*32 + u.
// Lane (cidx=batch, quad): D[m=4*quad+r] -> gate g, unit 8*quad + 4*(a&1) + r.
// Each lane therefore holds all 4 gates of units 8q..8q+7 for its batch, and
// after activations h packs directly into B-frag dwords: B[k=8q+j] = h[k].
//
// LDS: X @ 0: 16 rows x 1072B (67 16B-slots; 67%8=3 -> conflict-free b128
//      reads at per-step stride 32B). Z @ 17152: 32B zeros (x-frag quads 2,3).
//      fc2 scratch (16 x 144B) overlays X.
#define XSTRIDE 1072
#define ZOFF    (16 * XSTRIDE)
#define LDS_BYTES (ZOFF + 32)

typedef _Float16 f16x8 __attribute__((ext_vector_type(8)));
typedef __fp16   fp16x2 __attribute__((ext_vector_type(2)));
typedef float    f32x4 __attribute__((ext_vector_type(4)));
typedef float    f32x2 __attribute__((ext_vector_type(2)));

#define LOG2E     1.44269504088896f
#define TWO_LOG2E 2.88539008177793f

__global__ __launch_bounds__(64, 2)
void lstm_fused(const int* __restrict__ objs,
                const float* __restrict__ boxes,
                const int* __restrict__ preds,
                const int* __restrict__ subj,
                const float* __restrict__ obj_emb,
                const float* __restrict__ pred_emb,
                const float* __restrict__ W_ih,
                const float* __restrict__ W_hh,
                const float* __restrict__ b_ih,
                const float* __restrict__ b_hh,
                const float* __restrict__ fc2_W,
                const float* __restrict__ fc2_b,
                float* __restrict__ out)
{
    extern __shared__ char smem[];
    const int lane = threadIdx.x;        // 0..63
    const int quad = lane >> 4;          // 0..3: K-slice of MFMA frags
    const int cidx = lane & 15;          // batch column

    if (lane < 8) ((int*)(smem + ZOFF))[lane] = 0;

    // ---- stage x features (fp16) for this wave's 16 batches ----
    // thread (b = lane>>2, j = lane&3) handles t = j, j+4, ..., j+28:
    // stride-4 t gives conflict-free ds_write_b128 (slot%8 distinct per phase).
    {
        const int b = lane >> 2;
        const int j = lane & 3;
        const long gb = (long)blockIdx.x * 16 + b;
        const int* orow = objs + gb * 32;
        const int* prow = preds + gb * 32;
        const int* srow = subj + gb * 32;
        const float* brow = boxes + gb * 128;
        char* xrow = smem + b * XSTRIDE;
        #pragma unroll
        for (int tt = 0; tt < 8; ++tt) {
            int t = j + tt * 4;
            int o = orow[t], p = prow[t], sv = srow[t];
            const float* eo = obj_emb + o * 5;
            const float* ep = pred_emb + p * 5;
            float4 bx = *(const float4*)(brow + t * 4);
            f16x8 lo, hi;
            lo[0]=(_Float16)eo[0]; lo[1]=(_Float16)eo[1]; lo[2]=(_Float16)eo[2];
            lo[3]=(_Float16)eo[3]; lo[4]=(_Float16)eo[4];
            lo[5]=(_Float16)ep[0]; lo[6]=(_Float16)ep[1]; lo[7]=(_Float16)ep[2];
            hi[0]=(_Float16)ep[3]; hi[1]=(_Float16)ep[4];
            hi[2]=(_Float16)(sv==0 ? 1.0f : 0.0f);
            hi[3]=(_Float16)(sv==1 ? 1.0f : 0.0f);
            hi[4]=(_Float16)bx.x; hi[5]=(_Float16)bx.y;
            hi[6]=(_Float16)bx.z; hi[7]=(_Float16)bx.w;
            *(f16x8*)(xrow + t * 32)      = lo;
            *(f16x8*)(xrow + t * 32 + 16) = hi;
        }
    }

    // ---- W fragments + bias (vector float4 gathers; L1/L2-resident) ----
    // A-frag: lane holds A[row=cidx][k=quad*8+jj]; row n per permutation above.
    f16x8 WH[8], WX[8];
    f32x4 bias[8];
    #pragma unroll
    for (int a = 0; a < 8; ++a) {
        const int gate = a >> 1;
        const float scale = (gate == 2) ? TWO_LOG2E : -LOG2E;
        const int n = gate * 32 + 8 * (cidx >> 2) + 4 * (a & 1) + (cidx & 3);
        const float* wr = W_hh + n * 32 + quad * 8;
        float4 w0 = *(const float4*)(wr);
        float4 w1 = *(const float4*)(wr + 4);
        f16x8 h8;
        h8[0]=(_Float16)(w0.x*scale); h8[1]=(_Float16)(w0.y*scale);
        h8[2]=(_Float16)(w0.z*scale); h8[3]=(_Float16)(w0.w*scale);
        h8[4]=(_Float16)(w1.x*scale); h8[5]=(_Float16)(w1.y*scale);
        h8[6]=(_Float16)(w1.z*scale); h8[7]=(_Float16)(w1.w*scale);
        WH[a] = h8;
        f16x8 x8;
        if (quad < 2) {                  // k<16: W_ih columns; k>=16: zeros
            const float* xr = W_ih + n * 16 + quad * 8;
            float4 u0 = *(const float4*)(xr);
            float4 u1 = *(const float4*)(xr + 4);
            x8[0]=(_Float16)(u0.x*scale); x8[1]=(_Float16)(u0.y*scale);
            x8[2]=(_Float16)(u0.z*scale); x8[3]=(_Float16)(u0.w*scale);
            x8[4]=(_Float16)(u1.x*scale); x8[5]=(_Float16)(u1.y*scale);
            x8[6]=(_Float16)(u1.z*scale); x8[7]=(_Float16)(u1.w*scale);
        } else {
            #pragma unroll
            for (int jj = 0; jj < 8; ++jj) x8[jj] = (_Float16)0.0f;
        }
        WX[a] = x8;
        // bias rides as C of the x-MFMA: C-row 4*quad+r -> n = nb + r
        const int nb = gate * 32 + 8 * quad + 4 * (a & 1);
        float4 bi = *(const float4*)(b_ih + nb);
        float4 bh = *(const float4*)(b_hh + nb);
        f32x4 bb = {(bi.x+bh.x)*scale, (bi.y+bh.y)*scale,
                    (bi.z+bh.z)*scale, (bi.w+bh.w)*scale};
        bias[a] = bb;
    }

    __syncthreads();   // staging visible (1 wave; forces the waitcnt)

    // ---- recurrence: NO barriers, NO h exchange ----
    const bool qlow = (quad < 2);
    int xaddr = qlow ? (cidx * XSTRIDE + quad * 16) : ZOFF;
    const int xinc = qlow ? 32 : 0;

    f16x8 xfrag = *(const f16x8*)(smem + xaddr); xaddr += xinc;
    f32x4 accp[8];
    #pragma unroll
    for (int a = 0; a < 8; ++a)
        accp[a] = __builtin_amdgcn_mfma_f32_16x16x32_f16(WX[a], xfrag, bias[a], 0, 0, 0);

    union { int i[4]; f16x8 v; } hf;
    hf.i[0]=0; hf.i[1]=0; hf.i[2]=0; hf.i[3]=0;
    const f32x2 zz = {0.0f, 0.0f};
    f32x2 cst[4] = {zz, zz, zz, zz};
    f32x2 hv[4];
    const f32x2 one = {1.0f, 1.0f};

    #pragma unroll 4
    for (int t = 0; t < 32; ++t) {
        f32x4 acc[8];
        #pragma unroll
        for (int a = 0; a < 8; ++a)
            acc[a] = __builtin_amdgcn_mfma_f32_16x16x32_f16(WH[a], hf.v, accp[a], 0, 0, 0);

        // prefetch next x (t=31 reads row pad -> junk accp, discarded)
        f16x8 xn = *(const f16x8*)(smem + xaddr); xaddr += xinc;

        // 4 independent activation chains; chain cc -> units (8q+2cc, 8q+2cc+1)
        // gate values: i=acc[0+sel], f=acc[2+sel], g=acc[4+sel], o=acc[6+sel]
        // at regs (r0, r0+1) with sel=cc>>1, r0=(cc&1)*2.
        #pragma unroll
        for (int cc = 0; cc < 4; ++cc) {
            const int sel = cc >> 1;
            const int r0  = (cc & 1) << 1;
            f32x2 zi = {acc[0+sel][r0], acc[0+sel][r0+1]};
            f32x2 zf = {acc[2+sel][r0], acc[2+sel][r0+1]};
            f32x2 zg = {acc[4+sel][r0], acc[4+sel][r0+1]};
            f32x2 zo = {acc[6+sel][r0], acc[6+sel][r0+1]};
            f32x2 Ei = {__builtin_amdgcn_exp2f(zi.x), __builtin_amdgcn_exp2f(zi.y)};
            f32x2 Ef = {__builtin_amdgcn_exp2f(zf.x), __builtin_amdgcn_exp2f(zf.y)};
            f32x2 Eg = {__builtin_amdgcn_exp2f(zg.x), __builtin_amdgcn_exp2f(zg.y)};
            f32x2 Eo = {__builtin_amdgcn_exp2f(zo.x), __builtin_amdgcn_exp2f(zo.y)};
            f32x2 t1  = Ei + one;
            f32x2 dig = t1 * Eg + t1;                 // (1+Ei)(1+Eg)
            f32x2 tf  = Ef + one;
            f32x2 nn  = (Eg - one) * tf + cst[cc] * dig;
            f32x2 den = tf * dig;
            f32x2 rde = {__builtin_amdgcn_rcpf(den.x), __builtin_amdgcn_rcpf(den.y)};
            f32x2 c   = nn * rde;
            cst[cc] = c;
            f32x2 cl  = c * TWO_LOG2E;
            f32x2 Ec  = {__builtin_amdgcn_exp2f(cl.x), __builtin_amdgcn_exp2f(cl.y)};
            f32x2 to  = Eo + one;
            f32x2 dh  = to * Ec + to;                 // (1+Eo)(1+Ec)
            f32x2 rdh = {__builtin_amdgcn_rcpf(dh.x), __builtin_amdgcn_rcpf(dh.y)};
            hv[cc] = (Ec - one) * rdh;
            union { fp16x2 h; int i; } pk;
            pk.h = __builtin_amdgcn_cvt_pkrtz(hv[cc].x, hv[cc].y);
            hf.i[cc] = pk.i;   // dword cc = B-frag k = 8*quad + {2cc, 2cc+1}
        }

        // x-contribs for next step (independent of the chains; fills MFMA pipe)
        #pragma unroll
        for (int a = 0; a < 8; ++a)
            accp[a] = __builtin_amdgcn_mfma_f32_16x16x32_f16(WX[a], xn, bias[a], 0, 0, 0);
    }

    // ---- fc2 epilogue (wave-local; scratch overlays dead X region) ----
    __syncthreads();
    {
        // lane holds h (fp32) for units 8q..8q+7 of batch cidx, canonical order
        char* s0 = smem + cidx * 144 + quad * 32;    // stride 9 slots: no conflicts
        float4 lo4 = {hv[0].x, hv[0].y, hv[1].x, hv[1].y};
        float4 hi4 = {hv[2].x, hv[2].y, hv[3].x, hv[3].y};
        *(float4*)s0        = lo4;
        *(float4*)(s0 + 16) = hi4;
    }
    __syncthreads();
    {
        const int b = lane >> 2, j = lane & 3;       // one output per lane
        const float* hrow = (const float*)(smem + b * 144);
        const float* fw = fc2_W + j * 32;
        float s = fc2_b[j];
        #pragma unroll
        for (int k = 0; k < 8; ++k) {
            float4 hvv = *(const float4*)(hrow + k * 4);
            float4 wv4 = *(const float4*)(fw + k * 4);
            s += wv4.x*hvv.x + wv4.y*hvv.y + wv4.z*hvv.z + wv4.w*hvv.w;
        }
        s = fminf(fmaxf(s, 0.0f), 1.0f);
        out[(long)blockIdx.x * 64 + lane] = s;
    }
}

extern "C" void kernel_launch(void* const* d_in, const int* in_sizes, int n_in,
                              void* d_out, int out_size, void* d_ws, size_t ws_size,
                              hipStream_t stream)
{
    // inputs: 0 objs(i32) 1 boxes(f32) 2 preds(i32) 3 subj(i32) 4 target(unused)
    //         5 obj_emb 6 pred_emb 7 W_ih 8 W_hh 9 b_ih 10 b_hh 11 fc2_W 12 fc2_b
    lstm_fused<<<2048, 64, LDS_BYTES, stream>>>(
        (const int*)d_in[0], (const float*)d_in[1], (const int*)d_in[2],
        (const int*)d_in[3],
        (const float*)d_in[5], (const float*)d_in[6],
        (const float*)d_in[7], (const float*)d_in[8],
        (const float*)d_in[9], (const float*)d_in[10],
        (const float*)d_in[11], (const float*)d_in[12],
        (float*)d_out);
}